// Round 2
// baseline (657.334 us; speedup 1.0000x reference)
//
#include <hip/hip_runtime.h>

typedef __bf16 bf16x8 __attribute__((ext_vector_type(8)));
typedef unsigned short u16x8 __attribute__((ext_vector_type(8)));
typedef float f32x4 __attribute__((ext_vector_type(4)));
typedef unsigned short u16;

__device__ __forceinline__ float bf2f(u16 u) {
    union { unsigned int i; float f; } x; x.i = ((unsigned int)u) << 16; return x.f;
}
__device__ __forceinline__ u16 f2bf(float f) {
    union { float f; unsigned int i; } x; x.f = f;
    unsigned int u = x.i;
    unsigned int r = (u + 0x7FFFu + ((u >> 16) & 1u)) >> 16;
    return (u16)r;
}

#define GL16(g, l) __builtin_amdgcn_global_load_lds( \
    (__attribute__((address_space(1))) void*)(void*)(g), \
    (__attribute__((address_space(3))) void*)(void*)(l), 16, 0, 0)

// ---------------------------------------------------------------------------
// weights fp32 -> bf16; tensors 0-3: 262144 elems (128 blocks), 4-5: 1048576
// (512 blocks). 2048 elems/block. grid = 1536.
// ---------------------------------------------------------------------------
__global__ __launch_bounds__(256)
void cvt6_kernel(const float* __restrict__ s0, const float* __restrict__ s1,
                 const float* __restrict__ s2, const float* __restrict__ s3,
                 const float* __restrict__ s4, const float* __restrict__ s5,
                 u16* __restrict__ d0, u16* __restrict__ d1, u16* __restrict__ d2,
                 u16* __restrict__ d3, u16* __restrict__ d4, u16* __restrict__ d5)
{
    int b = blockIdx.x;
    const float* s; u16* d; int base;
    if (b < 512) {
        int t = b >> 7, lb = b & 127;
        s = (t == 0) ? s0 : (t == 1) ? s1 : (t == 2) ? s2 : s3;
        d = (t == 0) ? d0 : (t == 1) ? d1 : (t == 2) ? d2 : d3;
        base = lb * 2048;
    } else if (b < 1024) { s = s4; d = d4; base = (b - 512) * 2048; }
    else                 { s = s5; d = d5; base = (b - 1024) * 2048; }
    int i = base + threadIdx.x * 8;
    float4 a = *(const float4*)&s[i];
    float4 c = *(const float4*)&s[i + 4];
    u16x8 o;
    o[0] = f2bf(a.x); o[1] = f2bf(a.y); o[2] = f2bf(a.z); o[3] = f2bf(a.w);
    o[4] = f2bf(c.x); o[5] = f2bf(c.y); o[6] = f2bf(c.z); o[7] = f2bf(c.w);
    *(u16x8*)&d[i] = o;
}

// ---------------------------------------------------------------------------
// bias[i][j] = alpha * softmax_j(relu(E E^T))[i][j] + beta*lap + (lap!=0?0:-1e9)
// one block (256 thr) per row i; each thread owns j = tid and tid+256. fp32 in.
// ---------------------------------------------------------------------------
__global__ __launch_bounds__(256)
void bias_kernel(const float* __restrict__ E, const float* __restrict__ lap,
                 const float* __restrict__ alpha_p, const float* __restrict__ beta_p,
                 float* __restrict__ biasout)
{
    __shared__ float wred[8];
    int tid = threadIdx.x;
    int i = blockIdx.x;
    int lane = tid & 63, wave = tid >> 6;
    int j0 = tid, j1 = tid + 256;
    float s0 = 0.f, s1 = 0.f;
#pragma unroll
    for (int t4 = 0; t4 < 16; ++t4) {
        float4 a  = *(const float4*)&E[i * 64 + t4 * 4];
        float4 e0 = *(const float4*)&E[j0 * 64 + t4 * 4];
        float4 e1 = *(const float4*)&E[j1 * 64 + t4 * 4];
        s0 += a.x * e0.x + a.y * e0.y + a.z * e0.z + a.w * e0.w;
        s1 += a.x * e1.x + a.y * e1.y + a.z * e1.z + a.w * e1.w;
    }
    s0 = fmaxf(s0, 0.f); s1 = fmaxf(s1, 0.f);
    float m = fmaxf(s0, s1);
#pragma unroll
    for (int o = 32; o > 0; o >>= 1) m = fmaxf(m, __shfl_xor(m, o));
    if (lane == 0) wred[wave] = m;
    __syncthreads();
    m = fmaxf(fmaxf(wred[0], wred[1]), fmaxf(wred[2], wred[3]));
    float e0v = __expf(s0 - m), e1v = __expf(s1 - m);
    float sum = e0v + e1v;
#pragma unroll
    for (int o = 32; o > 0; o >>= 1) sum += __shfl_xor(sum, o);
    if (lane == 0) wred[4 + wave] = sum;
    __syncthreads();
    float inv = 1.f / (wred[4] + wred[5] + wred[6] + wred[7]);
    float alpha = alpha_p[0], beta = beta_p[0];
    float lv0 = lap[i * 512 + j0];
    float lv1 = lap[i * 512 + j1];
    biasout[i * 512 + j0] = alpha * (e0v * inv) + beta * lv0 + (lv0 != 0.f ? 0.f : -1e9f);
    biasout[i * 512 + j1] = alpha * (e1v * inv) + beta * lv1 + (lv1 != 0.f ? 0.f : -1e9f);
}

// ---------------------------------------------------------------------------
// LayerNorm over D=512, fp32 in, bf16 out; one wave per row, block = 4 waves
// ---------------------------------------------------------------------------
__global__ __launch_bounds__(256)
void ln_kernel(const float* __restrict__ X, const float* __restrict__ G,
               const float* __restrict__ Bb, u16* __restrict__ Y)
{
    int row = blockIdx.x * 4 + (threadIdx.x >> 6);
    int lane = threadIdx.x & 63;
    const float* xr = X + (size_t)row * 512 + lane * 8;
    float4 a = *(const float4*)xr;
    float4 b = *(const float4*)(xr + 4);
    float v[8] = {a.x, a.y, a.z, a.w, b.x, b.y, b.z, b.w};
    float s = 0.f, ss = 0.f;
#pragma unroll
    for (int i = 0; i < 8; i++) { s += v[i]; ss += v[i] * v[i]; }
#pragma unroll
    for (int o = 32; o > 0; o >>= 1) { s += __shfl_xor(s, o); ss += __shfl_xor(ss, o); }
    float mu = s * (1.f / 512.f);
    float var = ss * (1.f / 512.f) - mu * mu;
    float rstd = rsqrtf(var + 1e-5f);
    float4 g0 = *(const float4*)&G[lane * 8];
    float4 g1 = *(const float4*)&G[lane * 8 + 4];
    float4 b0 = *(const float4*)&Bb[lane * 8];
    float4 b1 = *(const float4*)&Bb[lane * 8 + 4];
    float gv[8] = {g0.x, g0.y, g0.z, g0.w, g1.x, g1.y, g1.z, g1.w};
    float bv[8] = {b0.x, b0.y, b0.z, b0.w, b1.x, b1.y, b1.z, b1.w};
    u16x8 out;
#pragma unroll
    for (int i = 0; i < 8; i++) out[i] = f2bf((v[i] - mu) * rstd * gv[i] + bv[i]);
    *(u16x8*)&Y[(size_t)row * 512 + lane * 8] = out;
}

// ---------------------------------------------------------------------------
// GEMM: A[M,Kd] bf16 @ W[Nout,Kd]^T bf16 + bias(fp32)
// 128x128 tile, 256 thr = 4 waves (2x2), each wave 4x4 of 16x16x32 MFMA.
// mode 0: Cb = bf16(result)          mode 1: Cb = bf16(relu(result))
// mode 2: Cf = result + resid (fp32)
// ---------------------------------------------------------------------------
__global__ __launch_bounds__(256)
void gemm_bt(const u16* __restrict__ A, const u16* __restrict__ W,
             const float* __restrict__ bias, const float* __restrict__ resid,
             u16* __restrict__ Cb, float* __restrict__ Cf,
             int M, int Kd, int Nout, int mode)
{
    __shared__ __align__(16) u16 lA[128 * 32];
    __shared__ __align__(16) u16 lB[128 * 32];
    int tid = threadIdx.x;
    int lane = tid & 63, wave = tid >> 6;
    int wm = wave >> 1, wn = wave & 1;
    int row0 = blockIdx.y * 128, col0 = blockIdx.x * 128;
    int rl = lane & 15, kq = lane >> 4;
    f32x4 acc[4][4];
#pragma unroll
    for (int i = 0; i < 4; i++)
#pragma unroll
        for (int j = 0; j < 4; j++) acc[i][j] = (f32x4){0.f, 0.f, 0.f, 0.f};

    int c0 = tid,       sr0 = c0 >> 2, sc0 = (c0 & 3) * 8;
    int c1 = 256 + tid, sr1 = c1 >> 2, sc1 = (c1 & 3) * 8;
    const u16* Abase = A + (size_t)row0 * Kd;
    const u16* Wbase = W + (size_t)col0 * Kd;

    for (int k0 = 0; k0 < Kd; k0 += 32) {
        GL16(Abase + (size_t)sr0 * Kd + k0 + sc0, &lA[c0 * 8]);
        GL16(Abase + (size_t)sr1 * Kd + k0 + sc1, &lA[c1 * 8]);
        GL16(Wbase + (size_t)sr0 * Kd + k0 + sc0, &lB[c0 * 8]);
        GL16(Wbase + (size_t)sr1 * Kd + k0 + sc1, &lB[c1 * 8]);
        __syncthreads();
        bf16x8 af[4], bf[4];
#pragma unroll
        for (int i = 0; i < 4; i++) af[i] = *(const bf16x8*)&lA[(wm * 64 + i * 16 + rl) * 32 + kq * 8];
#pragma unroll
        for (int j = 0; j < 4; j++) bf[j] = *(const bf16x8*)&lB[(wn * 64 + j * 16 + rl) * 32 + kq * 8];
#pragma unroll
        for (int i = 0; i < 4; i++)
#pragma unroll
            for (int j = 0; j < 4; j++)
                acc[i][j] = __builtin_amdgcn_mfma_f32_16x16x32_bf16(af[i], bf[j], acc[i][j], 0, 0, 0);
        __syncthreads();
    }
#pragma unroll
    for (int j = 0; j < 4; j++) {
        int col = col0 + wn * 64 + j * 16 + rl;
        float bsv = bias[col];
#pragma unroll
        for (int i = 0; i < 4; i++) {
            int rbase = row0 + wm * 64 + i * 16 + kq * 4;
#pragma unroll
            for (int r = 0; r < 4; r++) {
                float vo = acc[i][j][r] + bsv;
                size_t idx = (size_t)(rbase + r) * Nout + col;
                if (mode == 2)      Cf[idx] = vo + resid[idx];
                else if (mode == 1) Cb[idx] = f2bf(fmaxf(vo, 0.f));
                else                Cb[idx] = f2bf(vo);
            }
        }
    }
}

// ---------------------------------------------------------------------------
// attention per (b,t,head): 16 q-rows per block; scores->softmax->PV, all MFMA
// Q/K/V/O bf16, bias fp32. grid (32 row-tiles, 8 heads, 32 bt), block 256.
// ---------------------------------------------------------------------------
__global__ __launch_bounds__(256)
void attn_kernel(const u16* __restrict__ Q, const u16* __restrict__ Km,
                 const u16* __restrict__ V, const float* __restrict__ bias,
                 u16* __restrict__ O)
{
    __shared__ __align__(16) u16 lq[16 * 64];
    __shared__ __align__(16) float S[16 * 512];
    __shared__ __align__(16) u16 P[16 * 512];
    __shared__ __align__(16) u16 Vt[64 * 32];
    int tid = threadIdx.x, lane = tid & 63, wave = tid >> 6;
    int rl = lane & 15, kq = lane >> 4;
    int rt = blockIdx.x, h = blockIdx.y, bt = blockIdx.z;
    size_t base = (size_t)bt * (512 * 512) + h * 64;
    const u16* Qp = Q + base;
    const u16* Kp = Km + base;
    const u16* Vp = V + base;
    int row0 = rt * 16;

    if (tid < 128) {
        int r = tid >> 3, cc = (tid & 7) * 8;
        *(u16x8*)&lq[r * 64 + cc] = *(const u16x8*)&Qp[(size_t)(row0 + r) * 512 + cc];
    }
    __syncthreads();

    bf16x8 aq[2];
#pragma unroll
    for (int kk = 0; kk < 2; kk++) aq[kk] = *(const bf16x8*)&lq[rl * 64 + kk * 32 + kq * 8];
#pragma unroll
    for (int j = 0; j < 8; j++) {
        int mcol = wave * 128 + j * 16 + rl;
        const u16* krow = Kp + (size_t)mcol * 512;
        f32x4 a = (f32x4){0.f, 0.f, 0.f, 0.f};
#pragma unroll
        for (int kk = 0; kk < 2; kk++) {
            bf16x8 bk = *(const bf16x8*)&krow[kk * 32 + kq * 8];
            a = __builtin_amdgcn_mfma_f32_16x16x32_bf16(aq[kk], bk, a, 0, 0, 0);
        }
#pragma unroll
        for (int r = 0; r < 4; r++) {
            int row = kq * 4 + r;
            S[row * 512 + mcol] = a[r] * 0.125f + bias[(size_t)(row0 + row) * 512 + mcol];
        }
    }
    __syncthreads();

    {
        int srow = tid >> 4, seg = tid & 15;
        float* Sr = &S[srow * 512];
        float m = -3.0e38f;
#pragma unroll
        for (int c = 0; c < 32; c++) m = fmaxf(m, Sr[seg + c * 16]);
#pragma unroll
        for (int o = 1; o < 16; o <<= 1) m = fmaxf(m, __shfl_xor(m, o));
        float sum = 0.f;
#pragma unroll
        for (int c = 0; c < 32; c++) {
            float p = __expf(Sr[seg + c * 16] - m);
            Sr[seg + c * 16] = p;
            sum += p;
        }
#pragma unroll
        for (int o = 1; o < 16; o <<= 1) sum += __shfl_xor(sum, o);
        float inv = 1.f / sum;
        u16* Pr = &P[srow * 512];
#pragma unroll
        for (int c = 0; c < 32; c++) Pr[seg + c * 16] = f2bf(Sr[seg + c * 16] * inv);
    }
    __syncthreads();

    f32x4 accO = (f32x4){0.f, 0.f, 0.f, 0.f};
    for (int k0 = 0; k0 < 512; k0 += 32) {
        int mm = tid >> 3, e0 = (tid & 7) * 8;
        u16x8 vv = *(const u16x8*)&Vp[(size_t)(k0 + mm) * 512 + e0];
        __syncthreads();
#pragma unroll
        for (int u = 0; u < 8; u++) Vt[(e0 + u) * 32 + mm] = vv[u];
        __syncthreads();
        bf16x8 ap = *(const bf16x8*)&P[rl * 512 + k0 + kq * 8];
        bf16x8 bv = *(const bf16x8*)&Vt[(wave * 16 + rl) * 32 + kq * 8];
        accO = __builtin_amdgcn_mfma_f32_16x16x32_bf16(ap, bv, accO, 0, 0, 0);
    }
#pragma unroll
    for (int r = 0; r < 4; r++) {
        int row = kq * 4 + r;
        int e = wave * 16 + rl;
        O[base + (size_t)(row0 + row) * 512 + e] = f2bf(accO[r]);
    }
}

// ---------------------------------------------------------------------------
extern "C" void kernel_launch(void* const* d_in, const int* in_sizes, int n_in,
                              void* d_out, int out_size, void* d_ws, size_t ws_size,
                              hipStream_t stream)
{
    const float* x     = (const float*)d_in[0];
    const float* lap   = (const float*)d_in[1];
    const float* emb   = (const float*)d_in[2];
    const float* Wq    = (const float*)d_in[3];
    const float* bq    = (const float*)d_in[4];
    const float* Wk    = (const float*)d_in[5];
    const float* bk    = (const float*)d_in[6];
    const float* Wv    = (const float*)d_in[7];
    const float* bvv   = (const float*)d_in[8];
    const float* g1    = (const float*)d_in[9];
    const float* bb1   = (const float*)d_in[10];
    const float* g2    = (const float*)d_in[11];
    const float* bb2   = (const float*)d_in[12];
    const float* alpha = (const float*)d_in[13];
    const float* beta  = (const float*)d_in[14];
    const float* Wo    = (const float*)d_in[15];
    const float* bo    = (const float*)d_in[16];
    const float* W1    = (const float*)d_in[17];
    const float* b1    = (const float*)d_in[18];
    const float* W2    = (const float*)d_in[19];
    const float* b2    = (const float*)d_in[20];
    float* out = (float*)d_out;

    const size_t SZ = (size_t)4 * 8 * 512 * 512;   // 8,388,608 elements
    char* w = (char*)d_ws;
    float* bias = (float*)w;  w += (size_t)512 * 512 * 4;          // 1 MB
    u16* wqb = (u16*)w; w += (size_t)512 * 512 * 2;
    u16* wkb = (u16*)w; w += (size_t)512 * 512 * 2;
    u16* wvb = (u16*)w; w += (size_t)512 * 512 * 2;
    u16* wob = (u16*)w; w += (size_t)512 * 512 * 2;
    u16* w1b = (u16*)w; w += (size_t)2048 * 512 * 2;
    u16* w2b = (u16*)w; w += (size_t)512 * 2048 * 2;
    u16* xnb = (u16*)w; w += SZ * 2;   // LN1 out; reused as attention output
    u16* qb  = (u16*)w; w += SZ * 2;   // Q; reused as LN2 out
    u16* kb  = (u16*)w; w += SZ * 2;
    u16* vb  = (u16*)w; w += SZ * 2;
    u16* hb  = (u16*)w; w += (size_t)16384 * 2048 * 2;  // 64 MB
    float* x1 = out;                   // x1 lives in d_out (fp32)

    const int M = 16384;
    cvt6_kernel<<<1536, 256, 0, stream>>>(Wq, Wk, Wv, Wo, W1, W2,
                                          wqb, wkb, wvb, wob, w1b, w2b);
    bias_kernel<<<512, 256, 0, stream>>>(emb, lap, alpha, beta, bias);
    ln_kernel<<<M / 4, 256, 0, stream>>>(x, g1, bb1, xnb);
    dim3 g512(4, 128);
    gemm_bt<<<g512, 256, 0, stream>>>(xnb, wqb, bq, nullptr, qb, nullptr, M, 512, 512, 0);
    gemm_bt<<<g512, 256, 0, stream>>>(xnb, wkb, bk, nullptr, kb, nullptr, M, 512, 512, 0);
    gemm_bt<<<g512, 256, 0, stream>>>(xnb, wvb, bvv, nullptr, vb, nullptr, M, 512, 512, 0);
    attn_kernel<<<dim3(32, 8, 32), 256, 0, stream>>>(qb, kb, vb, bias, xnb);
    gemm_bt<<<g512, 256, 0, stream>>>(xnb, wob, bo, x, nullptr, x1, M, 512, 512, 2);
    ln_kernel<<<M / 4, 256, 0, stream>>>(x1, g2, bb2, qb);
    dim3 g2048(16, 128);
    gemm_bt<<<g2048, 256, 0, stream>>>(qb, w1b, b1, nullptr, hb, nullptr, M, 512, 2048, 1);
    gemm_bt<<<g512, 256, 0, stream>>>(hb, w2b, b2, x1, nullptr, out, M, 2048, 512, 2);
}

// Round 4
// 434.324 us; speedup vs baseline: 1.5135x; 1.5135x over previous
//
#include <hip/hip_runtime.h>

typedef __bf16 bf16x8 __attribute__((ext_vector_type(8)));
typedef unsigned short u16x8 __attribute__((ext_vector_type(8)));
typedef float f32x4 __attribute__((ext_vector_type(4)));
typedef unsigned short u16;

__device__ __forceinline__ float bf2f(u16 u) {
    union { unsigned int i; float f; } x; x.i = ((unsigned int)u) << 16; return x.f;
}
__device__ __forceinline__ u16 f2bf(float f) {
    union { float f; unsigned int i; } x; x.f = f;
    unsigned int u = x.i;
    unsigned int r = (u + 0x7FFFu + ((u >> 16) & 1u)) >> 16;
    return (u16)r;
}

#define GL16(g, l) __builtin_amdgcn_global_load_lds( \
    (__attribute__((address_space(1))) void*)(void*)(g), \
    (__attribute__((address_space(3))) void*)(void*)(l), 16, 0, 0)

// ---------------------------------------------------------------------------
// weights fp32 -> bf16
// ---------------------------------------------------------------------------
__global__ __launch_bounds__(256)
void cvt6_kernel(const float* __restrict__ s0, const float* __restrict__ s1,
                 const float* __restrict__ s2, const float* __restrict__ s3,
                 const float* __restrict__ s4, const float* __restrict__ s5,
                 u16* __restrict__ d0, u16* __restrict__ d1, u16* __restrict__ d2,
                 u16* __restrict__ d3, u16* __restrict__ d4, u16* __restrict__ d5)
{
    int b = blockIdx.x;
    const float* s; u16* d; int base;
    if (b < 512) {
        int t = b >> 7, lb = b & 127;
        s = (t == 0) ? s0 : (t == 1) ? s1 : (t == 2) ? s2 : s3;
        d = (t == 0) ? d0 : (t == 1) ? d1 : (t == 2) ? d2 : d3;
        base = lb * 2048;
    } else if (b < 1024) { s = s4; d = d4; base = (b - 512) * 2048; }
    else                 { s = s5; d = d5; base = (b - 1024) * 2048; }
    int i = base + threadIdx.x * 8;
    float4 a = *(const float4*)&s[i];
    float4 c = *(const float4*)&s[i + 4];
    u16x8 o;
    o[0] = f2bf(a.x); o[1] = f2bf(a.y); o[2] = f2bf(a.z); o[3] = f2bf(a.w);
    o[4] = f2bf(c.x); o[5] = f2bf(c.y); o[6] = f2bf(c.z); o[7] = f2bf(c.w);
    *(u16x8*)&d[i] = o;
}

// ---------------------------------------------------------------------------
// bias[i][j] = alpha*softmax_j(relu(E E^T)) + beta*lap + (lap!=0?0:-1e9)
// ---------------------------------------------------------------------------
__global__ __launch_bounds__(256)
void bias_kernel(const float* __restrict__ E, const float* __restrict__ lap,
                 const float* __restrict__ alpha_p, const float* __restrict__ beta_p,
                 float* __restrict__ biasout)
{
    __shared__ float wred[8];
    int tid = threadIdx.x;
    int i = blockIdx.x;
    int lane = tid & 63, wave = tid >> 6;
    int j0 = tid, j1 = tid + 256;
    float s0 = 0.f, s1 = 0.f;
#pragma unroll
    for (int t4 = 0; t4 < 16; ++t4) {
        float4 a  = *(const float4*)&E[i * 64 + t4 * 4];
        float4 e0 = *(const float4*)&E[j0 * 64 + t4 * 4];
        float4 e1 = *(const float4*)&E[j1 * 64 + t4 * 4];
        s0 += a.x * e0.x + a.y * e0.y + a.z * e0.z + a.w * e0.w;
        s1 += a.x * e1.x + a.y * e1.y + a.z * e1.z + a.w * e1.w;
    }
    s0 = fmaxf(s0, 0.f); s1 = fmaxf(s1, 0.f);
    float m = fmaxf(s0, s1);
#pragma unroll
    for (int o = 32; o > 0; o >>= 1) m = fmaxf(m, __shfl_xor(m, o));
    if (lane == 0) wred[wave] = m;
    __syncthreads();
    m = fmaxf(fmaxf(wred[0], wred[1]), fmaxf(wred[2], wred[3]));
    float e0v = __expf(s0 - m), e1v = __expf(s1 - m);
    float sum = e0v + e1v;
#pragma unroll
    for (int o = 32; o > 0; o >>= 1) sum += __shfl_xor(sum, o);
    if (lane == 0) wred[4 + wave] = sum;
    __syncthreads();
    float inv = 1.f / (wred[4] + wred[5] + wred[6] + wred[7]);
    float alpha = alpha_p[0], beta = beta_p[0];
    float lv0 = lap[i * 512 + j0];
    float lv1 = lap[i * 512 + j1];
    biasout[i * 512 + j0] = alpha * (e0v * inv) + beta * lv0 + (lv0 != 0.f ? 0.f : -1e9f);
    biasout[i * 512 + j1] = alpha * (e1v * inv) + beta * lv1 + (lv1 != 0.f ? 0.f : -1e9f);
}

// ---------------------------------------------------------------------------
// LayerNorm D=512, fp32 in, bf16 out
// ---------------------------------------------------------------------------
__global__ __launch_bounds__(256)
void ln_kernel(const float* __restrict__ X, const float* __restrict__ G,
               const float* __restrict__ Bb, u16* __restrict__ Y)
{
    int row = blockIdx.x * 4 + (threadIdx.x >> 6);
    int lane = threadIdx.x & 63;
    const float* xr = X + (size_t)row * 512 + lane * 8;
    float4 a = *(const float4*)xr;
    float4 b = *(const float4*)(xr + 4);
    float v[8] = {a.x, a.y, a.z, a.w, b.x, b.y, b.z, b.w};
    float s = 0.f, ss = 0.f;
#pragma unroll
    for (int i = 0; i < 8; i++) { s += v[i]; ss += v[i] * v[i]; }
#pragma unroll
    for (int o = 32; o > 0; o >>= 1) { s += __shfl_xor(s, o); ss += __shfl_xor(ss, o); }
    float mu = s * (1.f / 512.f);
    float var = ss * (1.f / 512.f) - mu * mu;
    float rstd = rsqrtf(var + 1e-5f);
    float4 g0 = *(const float4*)&G[lane * 8];
    float4 g1 = *(const float4*)&G[lane * 8 + 4];
    float4 b0 = *(const float4*)&Bb[lane * 8];
    float4 b1 = *(const float4*)&Bb[lane * 8 + 4];
    float gv[8] = {g0.x, g0.y, g0.z, g0.w, g1.x, g1.y, g1.z, g1.w};
    float bv[8] = {b0.x, b0.y, b0.z, b0.w, b1.x, b1.y, b1.z, b1.w};
    u16x8 out;
#pragma unroll
    for (int i = 0; i < 8; i++) out[i] = f2bf((v[i] - mu) * rstd * gv[i] + bv[i]);
    *(u16x8*)&Y[(size_t)row * 512 + lane * 8] = out;
}

// ---------------------------------------------------------------------------
// generic bf16 GEMM vs W^T (m97 pattern); mode 0 plain, 1 relu, 2 +=resid fp32
// ---------------------------------------------------------------------------
__global__ __launch_bounds__(256)
void gemm_bt(const u16* __restrict__ A, const u16* __restrict__ W,
             const float* __restrict__ bias, const float* __restrict__ resid,
             u16* __restrict__ Cb, float* __restrict__ Cf,
             int M, int Kd, int Nout, int mode)
{
    __shared__ __align__(16) u16 lA[128 * 32];
    __shared__ __align__(16) u16 lB[128 * 32];
    int tid = threadIdx.x;
    int lane = tid & 63, wave = tid >> 6;
    int wm = wave >> 1, wn = wave & 1;
    int row0 = blockIdx.y * 128, col0 = blockIdx.x * 128;
    int rl = lane & 15, kq = lane >> 4;
    f32x4 acc[4][4];
#pragma unroll
    for (int i = 0; i < 4; i++)
#pragma unroll
        for (int j = 0; j < 4; j++) acc[i][j] = (f32x4){0.f, 0.f, 0.f, 0.f};

    int c0 = tid,       sr0 = c0 >> 2, sc0 = (c0 & 3) * 8;
    int c1 = 256 + tid, sr1 = c1 >> 2, sc1 = (c1 & 3) * 8;
    const u16* Abase = A + (size_t)row0 * Kd;
    const u16* Wbase = W + (size_t)col0 * Kd;

    for (int k0 = 0; k0 < Kd; k0 += 32) {
        GL16(Abase + (size_t)sr0 * Kd + k0 + sc0, &lA[c0 * 8]);
        GL16(Abase + (size_t)sr1 * Kd + k0 + sc1, &lA[c1 * 8]);
        GL16(Wbase + (size_t)sr0 * Kd + k0 + sc0, &lB[c0 * 8]);
        GL16(Wbase + (size_t)sr1 * Kd + k0 + sc1, &lB[c1 * 8]);
        __syncthreads();
        bf16x8 af[4], bf[4];
#pragma unroll
        for (int i = 0; i < 4; i++) af[i] = *(const bf16x8*)&lA[(wm * 64 + i * 16 + rl) * 32 + kq * 8];
#pragma unroll
        for (int j = 0; j < 4; j++) bf[j] = *(const bf16x8*)&lB[(wn * 64 + j * 16 + rl) * 32 + kq * 8];
#pragma unroll
        for (int i = 0; i < 4; i++)
#pragma unroll
            for (int j = 0; j < 4; j++)
                acc[i][j] = __builtin_amdgcn_mfma_f32_16x16x32_bf16(af[i], bf[j], acc[i][j], 0, 0, 0);
        __syncthreads();
    }
#pragma unroll
    for (int j = 0; j < 4; j++) {
        int col = col0 + wn * 64 + j * 16 + rl;
        float bsv = bias[col];
#pragma unroll
        for (int i = 0; i < 4; i++) {
            int rbase = row0 + wm * 64 + i * 16 + kq * 4;
#pragma unroll
            for (int r = 0; r < 4; r++) {
                float vo = acc[i][j][r] + bsv;
                size_t idx = (size_t)(rbase + r) * Nout + col;
                if (mode == 2)      Cf[idx] = vo + resid[idx];
                else if (mode == 1) Cb[idx] = f2bf(fmaxf(vo, 0.f));
                else                Cb[idx] = f2bf(vo);
            }
        }
    }
}

// ---------------------------------------------------------------------------
// fused QKV: grid.x=12 -> sel = x>>2 picks (W,b,out), colblock = x&3
// ---------------------------------------------------------------------------
__global__ __launch_bounds__(256)
void gemm_qkv(const u16* __restrict__ A,
              const u16* __restrict__ W0, const u16* __restrict__ W1, const u16* __restrict__ W2,
              const float* __restrict__ b0, const float* __restrict__ b1, const float* __restrict__ b2,
              u16* __restrict__ C0, u16* __restrict__ C1, u16* __restrict__ C2)
{
    __shared__ __align__(16) u16 lA[128 * 32];
    __shared__ __align__(16) u16 lB[128 * 32];
    const int Kd = 512, Nout = 512;
    int sel = blockIdx.x >> 2;
    const u16* W = (sel == 0) ? W0 : (sel == 1) ? W1 : W2;
    const float* bias = (sel == 0) ? b0 : (sel == 1) ? b1 : b2;
    u16* Cb = (sel == 0) ? C0 : (sel == 1) ? C1 : C2;
    int tid = threadIdx.x;
    int lane = tid & 63, wave = tid >> 6;
    int wm = wave >> 1, wn = wave & 1;
    int row0 = blockIdx.y * 128, col0 = (blockIdx.x & 3) * 128;
    int rl = lane & 15, kq = lane >> 4;
    f32x4 acc[4][4];
#pragma unroll
    for (int i = 0; i < 4; i++)
#pragma unroll
        for (int j = 0; j < 4; j++) acc[i][j] = (f32x4){0.f, 0.f, 0.f, 0.f};
    int c0 = tid,       sr0 = c0 >> 2, sc0 = (c0 & 3) * 8;
    int c1 = 256 + tid, sr1 = c1 >> 2, sc1 = (c1 & 3) * 8;
    const u16* Abase = A + (size_t)row0 * Kd;
    const u16* Wbase = W + (size_t)col0 * Kd;
    for (int k0 = 0; k0 < Kd; k0 += 32) {
        GL16(Abase + (size_t)sr0 * Kd + k0 + sc0, &lA[c0 * 8]);
        GL16(Abase + (size_t)sr1 * Kd + k0 + sc1, &lA[c1 * 8]);
        GL16(Wbase + (size_t)sr0 * Kd + k0 + sc0, &lB[c0 * 8]);
        GL16(Wbase + (size_t)sr1 * Kd + k0 + sc1, &lB[c1 * 8]);
        __syncthreads();
        bf16x8 af[4], bf[4];
#pragma unroll
        for (int i = 0; i < 4; i++) af[i] = *(const bf16x8*)&lA[(wm * 64 + i * 16 + rl) * 32 + kq * 8];
#pragma unroll
        for (int j = 0; j < 4; j++) bf[j] = *(const bf16x8*)&lB[(wn * 64 + j * 16 + rl) * 32 + kq * 8];
#pragma unroll
        for (int i = 0; i < 4; i++)
#pragma unroll
            for (int j = 0; j < 4; j++)
                acc[i][j] = __builtin_amdgcn_mfma_f32_16x16x32_bf16(af[i], bf[j], acc[i][j], 0, 0, 0);
        __syncthreads();
    }
#pragma unroll
    for (int j = 0; j < 4; j++) {
        int col = col0 + wn * 64 + j * 16 + rl;
        float bsv = bias[col];
#pragma unroll
        for (int i = 0; i < 4; i++) {
            int rbase = row0 + wm * 64 + i * 16 + kq * 4;
#pragma unroll
            for (int r = 0; r < 4; r++)
                Cb[(size_t)(rbase + r) * Nout + col] = f2bf(acc[i][j][r] + bsv);
        }
    }
}

// ---------------------------------------------------------------------------
// flash attention: block = (qtile 128 rows) x (bt,h); 4 kv-tiles of 128,
// online softmax; O accum in regs. grid (4, 8, 32), block 256 (4 waves 2x2).
// ---------------------------------------------------------------------------
__global__ __launch_bounds__(256, 2)
void flash_attn(const u16* __restrict__ Q, const u16* __restrict__ Km,
                const u16* __restrict__ V, const float* __restrict__ biasP,
                u16* __restrict__ O)
{
    __shared__ __align__(16) u16 lQ[128 * 64];            // 16 KB [q][d]
    __shared__ __align__(16) u16 lPK[128 * 136];          // 34 KB: K tile (linear) / P (stride 136)
    __shared__ __align__(16) unsigned int lVt[64 * 68];   // 17 KB: V^T [e][kv-pair], stride 68 u32
    __shared__ float red[2 * 128];
    __shared__ float m_s[128], l_s[128], alpha_s[128], mnew_s[128];

    int tid = threadIdx.x, lane = tid & 63, wave = tid >> 6;
    int wm = wave >> 1, wn = wave & 1;
    int rl = lane & 15, kq = lane >> 4;
    int qt = blockIdx.x, h = blockIdx.y, bt = blockIdx.z;
    int qg0 = qt * 128;
    size_t hb = (size_t)bt * (512 * 512) + h * 64;
    const u16* Qbase = Q + hb + (size_t)qg0 * 512;
    const u16* Kb0   = Km + hb;
    const u16* Vb0   = V + hb;

    // stage Q (once)
#pragma unroll
    for (int rep = 0; rep < 4; ++rep) {
        int c = rep * 256 + tid;
        int qr = c >> 3, d0 = (c & 7) * 8;
        GL16(Qbase + (size_t)qr * 512 + d0, &lQ[c * 8]);
    }
    if (tid < 128) { m_s[tid] = -3.0e38f; l_s[tid] = 0.f; }
    __syncthreads();

    bf16x8 af[4][2];
#pragma unroll
    for (int i = 0; i < 4; i++)
#pragma unroll
        for (int s = 0; s < 2; s++)
            af[i][s] = *(const bf16x8*)&lQ[(wm * 64 + i * 16 + rl) * 64 + s * 32 + kq * 8];

    f32x4 o[4][2];
#pragma unroll
    for (int i = 0; i < 4; i++)
#pragma unroll
        for (int jj = 0; jj < 2; jj++) o[i][jj] = (f32x4){0.f, 0.f, 0.f, 0.f};

    for (int t = 0; t < 4; ++t) {
        int kv0 = t * 128;
        __syncthreads();   // prior PV reads of lPK/lVt done
        // stage K tile -> lPK (linear [kv][64])
        const u16* Kbase = Kb0 + (size_t)kv0 * 512;
#pragma unroll
        for (int rep = 0; rep < 4; ++rep) {
            int c = rep * 256 + tid;
            int kv = c >> 3, d0 = (c & 7) * 8;
            GL16(Kbase + (size_t)kv * 512 + d0, &lPK[c * 8]);
        }
        // stage V^T (paired-row b32 writes, bank = p%32 -> 2-way, free)
        const u16* Vbase = Vb0 + (size_t)kv0 * 512;
#pragma unroll
        for (int rep = 0; rep < 2; ++rep) {
            int idx = rep * 256 + tid;
            int p = idx & 63, e0 = (idx >> 6) * 8;
            const u16* vp0 = Vbase + (size_t)(2 * p) * 512 + e0;
            u16x8 v0 = *(const u16x8*)vp0;
            u16x8 v1 = *(const u16x8*)(vp0 + 512);
#pragma unroll
            for (int u = 0; u < 8; ++u)
                lVt[(e0 + u) * 68 + p] = (unsigned)v0[u] | ((unsigned)v1[u] << 16);
        }
        __syncthreads();   // staging complete

        // S = Q K^T * 0.125 + bias
        f32x4 acc[4][4];
#pragma unroll
        for (int j = 0; j < 4; ++j) {
            bf16x8 bk0 = *(const bf16x8*)&lPK[(wn * 64 + j * 16 + rl) * 64 + kq * 8];
            bf16x8 bk1 = *(const bf16x8*)&lPK[(wn * 64 + j * 16 + rl) * 64 + 32 + kq * 8];
#pragma unroll
            for (int i = 0; i < 4; ++i) {
                acc[i][j] = __builtin_amdgcn_mfma_f32_16x16x32_bf16(af[i][0], bk0,
                            (f32x4){0.f, 0.f, 0.f, 0.f}, 0, 0, 0);
                acc[i][j] = __builtin_amdgcn_mfma_f32_16x16x32_bf16(af[i][1], bk1, acc[i][j], 0, 0, 0);
            }
        }
#pragma unroll
        for (int i = 0; i < 4; ++i)
#pragma unroll
            for (int j = 0; j < 4; ++j) {
                int colg = kv0 + wn * 64 + j * 16 + rl;
                const float* bp = biasP + (size_t)(qg0 + wm * 64 + i * 16 + kq * 4) * 512 + colg;
#pragma unroll
                for (int r = 0; r < 4; ++r)
                    acc[i][j][r] = acc[i][j][r] * 0.125f + bp[(size_t)r * 512];
            }

        // per-tile row max -> red
#pragma unroll
        for (int i = 0; i < 4; ++i) {
            float mx[4];
#pragma unroll
            for (int r = 0; r < 4; ++r) {
                mx[r] = fmaxf(fmaxf(acc[i][0][r], acc[i][1][r]), fmaxf(acc[i][2][r], acc[i][3][r]));
#pragma unroll
                for (int off = 8; off > 0; off >>= 1) mx[r] = fmaxf(mx[r], __shfl_xor(mx[r], off));
            }
            if (rl == 0) {
#pragma unroll
                for (int r = 0; r < 4; ++r)
                    red[wn * 128 + wm * 64 + i * 16 + kq * 4 + r] = mx[r];
            }
        }
        __syncthreads();
        if (tid < 128) {
            float pm = fmaxf(red[tid], red[128 + tid]);
            float mo = m_s[tid];
            float mn = fmaxf(mo, pm);
            m_s[tid] = mn; mnew_s[tid] = mn;
            alpha_s[tid] = __expf(mo - mn);
        }
        __syncthreads();

        // P = exp(S - m_new); write lP; row sums; rescale O
#pragma unroll
        for (int i = 0; i < 4; ++i) {
            int rb = wm * 64 + i * 16 + kq * 4;
            float mn[4], al[4], sm[4];
#pragma unroll
            for (int r = 0; r < 4; ++r) { mn[r] = mnew_s[rb + r]; al[r] = alpha_s[rb + r]; sm[r] = 0.f; }
#pragma unroll
            for (int j = 0; j < 4; ++j) {
                int col = wn * 64 + j * 16 + rl;
#pragma unroll
                for (int r = 0; r < 4; ++r) {
                    float p = __expf(acc[i][j][r] - mn[r]);
                    sm[r] += p;
                    lPK[(rb + r) * 136 + col] = f2bf(p);
                }
            }
#pragma unroll
            for (int jj = 0; jj < 2; ++jj)
#pragma unroll
                for (int r = 0; r < 4; ++r) o[i][jj][r] *= al[r];
#pragma unroll
            for (int r = 0; r < 4; ++r) {
#pragma unroll
                for (int off = 8; off > 0; off >>= 1) sm[r] += __shfl_xor(sm[r], off);
            }
            if (rl == 0) {
#pragma unroll
                for (int r = 0; r < 4; ++r) red[wn * 128 + rb + r] = sm[r];
            }
        }
        __syncthreads();
        if (tid < 128) l_s[tid] = l_s[tid] * alpha_s[tid] + red[tid] + red[128 + tid];

        // O += P V  (A-frags from lP stride 136; B-frags from lVt:
        //  kv pairs packed in u32 -> u32 offset X must satisfy 2X = ks*32+kq*8)
#pragma unroll
        for (int ks = 0; ks < 4; ++ks) {
            bf16x8 aP[4], bV[2];
#pragma unroll
            for (int i = 0; i < 4; ++i)
                aP[i] = *(const bf16x8*)&lPK[(wm * 64 + i * 16 + rl) * 136 + ks * 32 + kq * 8];
#pragma unroll
            for (int jj = 0; jj < 2; ++jj)
                bV[jj] = *(const bf16x8*)&lVt[(wn * 32 + jj * 16 + rl) * 68 + ks * 16 + kq * 4];
#pragma unroll
            for (int i = 0; i < 4; ++i)
#pragma unroll
                for (int jj = 0; jj < 2; ++jj)
                    o[i][jj] = __builtin_amdgcn_mfma_f32_16x16x32_bf16(aP[i], bV[jj], o[i][jj], 0, 0, 0);
        }
    }
    __syncthreads();

    // epilogue: O /= l, write bf16
    u16* Ob = O + hb + (size_t)qg0 * 512;
#pragma unroll
    for (int i = 0; i < 4; ++i) {
        int rb = wm * 64 + i * 16 + kq * 4;
        float il[4];
#pragma unroll
        for (int r = 0; r < 4; ++r) il[r] = 1.f / l_s[rb + r];
#pragma unroll
        for (int jj = 0; jj < 2; ++jj) {
            int e = wn * 32 + jj * 16 + rl;
#pragma unroll
            for (int r = 0; r < 4; ++r)
                Ob[(size_t)(rb + r) * 512 + e] = f2bf(o[i][jj][r] * il[r]);
        }
    }
}

// ---------------------------------------------------------------------------
extern "C" void kernel_launch(void* const* d_in, const int* in_sizes, int n_in,
                              void* d_out, int out_size, void* d_ws, size_t ws_size,
                              hipStream_t stream)
{
    const float* x     = (const float*)d_in[0];
    const float* lap   = (const float*)d_in[1];
    const float* emb   = (const float*)d_in[2];
    const float* Wq    = (const float*)d_in[3];
    const float* bq    = (const float*)d_in[4];
    const float* Wk    = (const float*)d_in[5];
    const float* bk    = (const float*)d_in[6];
    const float* Wv    = (const float*)d_in[7];
    const float* bvv   = (const float*)d_in[8];
    const float* g1    = (const float*)d_in[9];
    const float* bb1   = (const float*)d_in[10];
    const float* g2    = (const float*)d_in[11];
    const float* bb2   = (const float*)d_in[12];
    const float* alpha = (const float*)d_in[13];
    const float* beta  = (const float*)d_in[14];
    const float* Wo    = (const float*)d_in[15];
    const float* bo    = (const float*)d_in[16];
    const float* W1    = (const float*)d_in[17];
    const float* b1    = (const float*)d_in[18];
    const float* W2    = (const float*)d_in[19];
    const float* b2    = (const float*)d_in[20];
    float* out = (float*)d_out;

    const size_t SZ = (size_t)4 * 8 * 512 * 512;
    char* w = (char*)d_ws;
    float* bias = (float*)w;  w += (size_t)512 * 512 * 4;
    u16* wqb = (u16*)w; w += (size_t)512 * 512 * 2;
    u16* wkb = (u16*)w; w += (size_t)512 * 512 * 2;
    u16* wvb = (u16*)w; w += (size_t)512 * 512 * 2;
    u16* wob = (u16*)w; w += (size_t)512 * 512 * 2;
    u16* w1b = (u16*)w; w += (size_t)2048 * 512 * 2;
    u16* w2b = (u16*)w; w += (size_t)512 * 2048 * 2;
    u16* xnb = (u16*)w; w += SZ * 2;   // LN1 out; reused as attention output
    u16* qb  = (u16*)w; w += SZ * 2;   // Q; reused as LN2 out
    u16* kb  = (u16*)w; w += SZ * 2;
    u16* vb  = (u16*)w; w += SZ * 2;
    u16* hb  = (u16*)w; w += (size_t)16384 * 2048 * 2;
    float* x1 = out;

    const int M = 16384;
    cvt6_kernel<<<1536, 256, 0, stream>>>(Wq, Wk, Wv, Wo, W1, W2,
                                          wqb, wkb, wvb, wob, w1b, w2b);
    bias_kernel<<<512, 256, 0, stream>>>(emb, lap, alpha, beta, bias);
    ln_kernel<<<M / 4, 256, 0, stream>>>(x, g1, bb1, xnb);
    gemm_qkv<<<dim3(12, 128), 256, 0, stream>>>(xnb, wqb, wkb, wvb, bq, bk, bvv, qb, kb, vb);
    flash_attn<<<dim3(4, 8, 32), 256, 0, stream>>>(qb, kb, vb, bias, xnb);
    gemm_bt<<<dim3(4, 128), 256, 0, stream>>>(xnb, wob, bo, x, nullptr, x1, M, 512, 512, 2);
    ln_kernel<<<M / 4, 256, 0, stream>>>(x1, g2, bb2, qb);
    gemm_bt<<<dim3(16, 128), 256, 0, stream>>>(qb, w1b, b1, nullptr, hb, nullptr, M, 512, 2048, 1);
    gemm_bt<<<dim3(4, 128), 256, 0, stream>>>(hb, w2b, b2, x1, nullptr, out, M, 2048, 512, 2);
}

// Round 5
// 427.393 us; speedup vs baseline: 1.5380x; 1.0162x over previous
//
#include <hip/hip_runtime.h>

typedef __bf16 bf16x8 __attribute__((ext_vector_type(8)));
typedef unsigned short u16x8 __attribute__((ext_vector_type(8)));
typedef float f32x4 __attribute__((ext_vector_type(4)));
typedef unsigned short u16;

__device__ __forceinline__ float bf2f(u16 u) {
    union { unsigned int i; float f; } x; x.i = ((unsigned int)u) << 16; return x.f;
}
__device__ __forceinline__ u16 f2bf(float f) {
    union { float f; unsigned int i; } x; x.f = f;
    unsigned int u = x.i;
    unsigned int r = (u + 0x7FFFu + ((u >> 16) & 1u)) >> 16;
    return (u16)r;
}

#define GL16(g, l) __builtin_amdgcn_global_load_lds( \
    (__attribute__((address_space(1))) void*)(void*)(g), \
    (__attribute__((address_space(3))) void*)(void*)(l), 16, 0, 0)

// ---------------------------------------------------------------------------
// weights fp32 -> bf16
// ---------------------------------------------------------------------------
__global__ __launch_bounds__(256)
void cvt6_kernel(const float* __restrict__ s0, const float* __restrict__ s1,
                 const float* __restrict__ s2, const float* __restrict__ s3,
                 const float* __restrict__ s4, const float* __restrict__ s5,
                 u16* __restrict__ d0, u16* __restrict__ d1, u16* __restrict__ d2,
                 u16* __restrict__ d3, u16* __restrict__ d4, u16* __restrict__ d5)
{
    int b = blockIdx.x;
    const float* s; u16* d; int base;
    if (b < 512) {
        int t = b >> 7, lb = b & 127;
        s = (t == 0) ? s0 : (t == 1) ? s1 : (t == 2) ? s2 : s3;
        d = (t == 0) ? d0 : (t == 1) ? d1 : (t == 2) ? d2 : d3;
        base = lb * 2048;
    } else if (b < 1024) { s = s4; d = d4; base = (b - 512) * 2048; }
    else                 { s = s5; d = d5; base = (b - 1024) * 2048; }
    int i = base + threadIdx.x * 8;
    float4 a = *(const float4*)&s[i];
    float4 c = *(const float4*)&s[i + 4];
    u16x8 o;
    o[0] = f2bf(a.x); o[1] = f2bf(a.y); o[2] = f2bf(a.z); o[3] = f2bf(a.w);
    o[4] = f2bf(c.x); o[5] = f2bf(c.y); o[6] = f2bf(c.z); o[7] = f2bf(c.w);
    *(u16x8*)&d[i] = o;
}

// ---------------------------------------------------------------------------
// bias[i][j] = alpha*softmax_j(relu(E E^T)) + beta*lap + (lap!=0?0:-1e9)
// ---------------------------------------------------------------------------
__global__ __launch_bounds__(256)
void bias_kernel(const float* __restrict__ E, const float* __restrict__ lap,
                 const float* __restrict__ alpha_p, const float* __restrict__ beta_p,
                 float* __restrict__ biasout)
{
    __shared__ float wred[8];
    int tid = threadIdx.x;
    int i = blockIdx.x;
    int lane = tid & 63, wave = tid >> 6;
    int j0 = tid, j1 = tid + 256;
    float s0 = 0.f, s1 = 0.f;
#pragma unroll
    for (int t4 = 0; t4 < 16; ++t4) {
        float4 a  = *(const float4*)&E[i * 64 + t4 * 4];
        float4 e0 = *(const float4*)&E[j0 * 64 + t4 * 4];
        float4 e1 = *(const float4*)&E[j1 * 64 + t4 * 4];
        s0 += a.x * e0.x + a.y * e0.y + a.z * e0.z + a.w * e0.w;
        s1 += a.x * e1.x + a.y * e1.y + a.z * e1.z + a.w * e1.w;
    }
    s0 = fmaxf(s0, 0.f); s1 = fmaxf(s1, 0.f);
    float m = fmaxf(s0, s1);
#pragma unroll
    for (int o = 32; o > 0; o >>= 1) m = fmaxf(m, __shfl_xor(m, o));
    if (lane == 0) wred[wave] = m;
    __syncthreads();
    m = fmaxf(fmaxf(wred[0], wred[1]), fmaxf(wred[2], wred[3]));
    float e0v = __expf(s0 - m), e1v = __expf(s1 - m);
    float sum = e0v + e1v;
#pragma unroll
    for (int o = 32; o > 0; o >>= 1) sum += __shfl_xor(sum, o);
    if (lane == 0) wred[4 + wave] = sum;
    __syncthreads();
    float inv = 1.f / (wred[4] + wred[5] + wred[6] + wred[7]);
    float alpha = alpha_p[0], beta = beta_p[0];
    float lv0 = lap[i * 512 + j0];
    float lv1 = lap[i * 512 + j1];
    biasout[i * 512 + j0] = alpha * (e0v * inv) + beta * lv0 + (lv0 != 0.f ? 0.f : -1e9f);
    biasout[i * 512 + j1] = alpha * (e1v * inv) + beta * lv1 + (lv1 != 0.f ? 0.f : -1e9f);
}

// ---------------------------------------------------------------------------
// LayerNorm D=512, fp32 in, bf16 out
// ---------------------------------------------------------------------------
__global__ __launch_bounds__(256)
void ln_kernel(const float* __restrict__ X, const float* __restrict__ G,
               const float* __restrict__ Bb, u16* __restrict__ Y)
{
    int row = blockIdx.x * 4 + (threadIdx.x >> 6);
    int lane = threadIdx.x & 63;
    const float* xr = X + (size_t)row * 512 + lane * 8;
    float4 a = *(const float4*)xr;
    float4 b = *(const float4*)(xr + 4);
    float v[8] = {a.x, a.y, a.z, a.w, b.x, b.y, b.z, b.w};
    float s = 0.f, ss = 0.f;
#pragma unroll
    for (int i = 0; i < 8; i++) { s += v[i]; ss += v[i] * v[i]; }
#pragma unroll
    for (int o = 32; o > 0; o >>= 1) { s += __shfl_xor(s, o); ss += __shfl_xor(ss, o); }
    float mu = s * (1.f / 512.f);
    float var = ss * (1.f / 512.f) - mu * mu;
    float rstd = rsqrtf(var + 1e-5f);
    float4 g0 = *(const float4*)&G[lane * 8];
    float4 g1 = *(const float4*)&G[lane * 8 + 4];
    float4 b0 = *(const float4*)&Bb[lane * 8];
    float4 b1 = *(const float4*)&Bb[lane * 8 + 4];
    float gv[8] = {g0.x, g0.y, g0.z, g0.w, g1.x, g1.y, g1.z, g1.w};
    float bv[8] = {b0.x, b0.y, b0.z, b0.w, b1.x, b1.y, b1.z, b1.w};
    u16x8 out;
#pragma unroll
    for (int i = 0; i < 8; i++) out[i] = f2bf((v[i] - mu) * rstd * gv[i] + bv[i]);
    *(u16x8*)&Y[(size_t)row * 512 + lane * 8] = out;
}

// ---------------------------------------------------------------------------
// generic bf16 GEMM vs W^T (m97 pattern); mode 0 plain, 1 relu, 2 +=resid fp32
// XCD-swizzled: each XCD owns a contiguous slab of row-panels so the A-panel
// is fetched into exactly one XCD's L2 (was ~8x duplicated).
// ---------------------------------------------------------------------------
__global__ __launch_bounds__(256)
void gemm_bt(const u16* __restrict__ A, const u16* __restrict__ W,
             const float* __restrict__ bias, const float* __restrict__ resid,
             u16* __restrict__ Cb, float* __restrict__ Cf,
             int M, int Kd, int Nout, int mode)
{
    __shared__ __align__(16) u16 lA[128 * 32];
    __shared__ __align__(16) u16 lB[128 * 32];
    int tid = threadIdx.x;
    int lane = tid & 63, wave = tid >> 6;
    int wm = wave >> 1, wn = wave & 1;
    // XCD swizzle: bid%8 = XCD (round-robin dispatch); give each XCD
    // a contiguous range of logical blocks (row-major, col fastest).
    int bid = blockIdx.y * gridDim.x + blockIdx.x;
    int per = (gridDim.x * gridDim.y) >> 3;
    int lb  = (bid & 7) * per + (bid >> 3);
    int bx = lb % gridDim.x, by = lb / gridDim.x;
    int row0 = by * 128, col0 = bx * 128;
    int rl = lane & 15, kq = lane >> 4;
    f32x4 acc[4][4];
#pragma unroll
    for (int i = 0; i < 4; i++)
#pragma unroll
        for (int j = 0; j < 4; j++) acc[i][j] = (f32x4){0.f, 0.f, 0.f, 0.f};

    int c0 = tid,       sr0 = c0 >> 2, sc0 = (c0 & 3) * 8;
    int c1 = 256 + tid, sr1 = c1 >> 2, sc1 = (c1 & 3) * 8;
    const u16* Abase = A + (size_t)row0 * Kd;
    const u16* Wbase = W + (size_t)col0 * Kd;

    for (int k0 = 0; k0 < Kd; k0 += 32) {
        GL16(Abase + (size_t)sr0 * Kd + k0 + sc0, &lA[c0 * 8]);
        GL16(Abase + (size_t)sr1 * Kd + k0 + sc1, &lA[c1 * 8]);
        GL16(Wbase + (size_t)sr0 * Kd + k0 + sc0, &lB[c0 * 8]);
        GL16(Wbase + (size_t)sr1 * Kd + k0 + sc1, &lB[c1 * 8]);
        __syncthreads();
        bf16x8 af[4], bf[4];
#pragma unroll
        for (int i = 0; i < 4; i++) af[i] = *(const bf16x8*)&lA[(wm * 64 + i * 16 + rl) * 32 + kq * 8];
#pragma unroll
        for (int j = 0; j < 4; j++) bf[j] = *(const bf16x8*)&lB[(wn * 64 + j * 16 + rl) * 32 + kq * 8];
#pragma unroll
        for (int i = 0; i < 4; i++)
#pragma unroll
            for (int j = 0; j < 4; j++)
                acc[i][j] = __builtin_amdgcn_mfma_f32_16x16x32_bf16(af[i], bf[j], acc[i][j], 0, 0, 0);
        __syncthreads();
    }
#pragma unroll
    for (int j = 0; j < 4; j++) {
        int col = col0 + wn * 64 + j * 16 + rl;
        float bsv = bias[col];
#pragma unroll
        for (int i = 0; i < 4; i++) {
            int rbase = row0 + wm * 64 + i * 16 + kq * 4;
#pragma unroll
            for (int r = 0; r < 4; r++) {
                float vo = acc[i][j][r] + bsv;
                size_t idx = (size_t)(rbase + r) * Nout + col;
                if (mode == 2)      Cf[idx] = vo + resid[idx];
                else if (mode == 1) Cb[idx] = f2bf(fmaxf(vo, 0.f));
                else                Cb[idx] = f2bf(vo);
            }
        }
    }
}

// ---------------------------------------------------------------------------
// fused QKV, XCD-swizzled: all 12 (sel,col) blocks of a row-slab co-locate
// per XCD so the shared A-panel is fetched once.
// ---------------------------------------------------------------------------
__global__ __launch_bounds__(256)
void gemm_qkv(const u16* __restrict__ A,
              const u16* __restrict__ W0, const u16* __restrict__ W1, const u16* __restrict__ W2,
              const float* __restrict__ b0, const float* __restrict__ b1, const float* __restrict__ b2,
              u16* __restrict__ C0, u16* __restrict__ C1, u16* __restrict__ C2)
{
    __shared__ __align__(16) u16 lA[128 * 32];
    __shared__ __align__(16) u16 lB[128 * 32];
    const int Kd = 512, Nout = 512;
    int bid = blockIdx.y * gridDim.x + blockIdx.x;
    int per = (gridDim.x * gridDim.y) >> 3;       // 192
    int lb  = (bid & 7) * per + (bid >> 3);
    int rest = lb % 12, by = lb / 12;
    int sel = rest >> 2;
    const u16* W = (sel == 0) ? W0 : (sel == 1) ? W1 : W2;
    const float* bias = (sel == 0) ? b0 : (sel == 1) ? b1 : b2;
    u16* Cb = (sel == 0) ? C0 : (sel == 1) ? C1 : C2;
    int tid = threadIdx.x;
    int lane = tid & 63, wave = tid >> 6;
    int wm = wave >> 1, wn = wave & 1;
    int row0 = by * 128, col0 = (rest & 3) * 128;
    int rl = lane & 15, kq = lane >> 4;
    f32x4 acc[4][4];
#pragma unroll
    for (int i = 0; i < 4; i++)
#pragma unroll
        for (int j = 0; j < 4; j++) acc[i][j] = (f32x4){0.f, 0.f, 0.f, 0.f};
    int c0 = tid,       sr0 = c0 >> 2, sc0 = (c0 & 3) * 8;
    int c1 = 256 + tid, sr1 = c1 >> 2, sc1 = (c1 & 3) * 8;
    const u16* Abase = A + (size_t)row0 * Kd;
    const u16* Wbase = W + (size_t)col0 * Kd;
    for (int k0 = 0; k0 < Kd; k0 += 32) {
        GL16(Abase + (size_t)sr0 * Kd + k0 + sc0, &lA[c0 * 8]);
        GL16(Abase + (size_t)sr1 * Kd + k0 + sc1, &lA[c1 * 8]);
        GL16(Wbase + (size_t)sr0 * Kd + k0 + sc0, &lB[c0 * 8]);
        GL16(Wbase + (size_t)sr1 * Kd + k0 + sc1, &lB[c1 * 8]);
        __syncthreads();
        bf16x8 af[4], bf[4];
#pragma unroll
        for (int i = 0; i < 4; i++) af[i] = *(const bf16x8*)&lA[(wm * 64 + i * 16 + rl) * 32 + kq * 8];
#pragma unroll
        for (int j = 0; j < 4; j++) bf[j] = *(const bf16x8*)&lB[(wn * 64 + j * 16 + rl) * 32 + kq * 8];
#pragma unroll
        for (int i = 0; i < 4; i++)
#pragma unroll
            for (int j = 0; j < 4; j++)
                acc[i][j] = __builtin_amdgcn_mfma_f32_16x16x32_bf16(af[i], bf[j], acc[i][j], 0, 0, 0);
        __syncthreads();
    }
#pragma unroll
    for (int j = 0; j < 4; j++) {
        int col = col0 + wn * 64 + j * 16 + rl;
        float bsv = bias[col];
#pragma unroll
        for (int i = 0; i < 4; i++) {
            int rbase = row0 + wm * 64 + i * 16 + kq * 4;
#pragma unroll
            for (int r = 0; r < 4; r++)
                Cb[(size_t)(rbase + r) * Nout + col] = f2bf(acc[i][j][r] + bsv);
        }
    }
}

// ---------------------------------------------------------------------------
// flash attention: block = (qtile 128 rows) x (bt,h); 4 kv-tiles of 128,
// online softmax; O accum in regs. grid (4, 8, 32), block 256 (4 waves 2x2).
// ---------------------------------------------------------------------------
__global__ __launch_bounds__(256, 2)
void flash_attn(const u16* __restrict__ Q, const u16* __restrict__ Km,
                const u16* __restrict__ V, const float* __restrict__ biasP,
                u16* __restrict__ O)
{
    __shared__ __align__(16) u16 lQ[128 * 64];            // 16 KB [q][d]
    __shared__ __align__(16) u16 lPK[128 * 136];          // 34 KB: K tile (linear) / P (stride 136)
    __shared__ __align__(16) unsigned int lVt[64 * 68];   // 17 KB: V^T [e][kv-pair], stride 68 u32
    __shared__ float red[2 * 128];
    __shared__ float m_s[128], l_s[128], alpha_s[128], mnew_s[128];

    int tid = threadIdx.x, lane = tid & 63, wave = tid >> 6;
    int wm = wave >> 1, wn = wave & 1;
    int rl = lane & 15, kq = lane >> 4;
    int qt = blockIdx.x, h = blockIdx.y, bt = blockIdx.z;
    int qg0 = qt * 128;
    size_t hb = (size_t)bt * (512 * 512) + h * 64;
    const u16* Qbase = Q + hb + (size_t)qg0 * 512;
    const u16* Kb0   = Km + hb;
    const u16* Vb0   = V + hb;

    // stage Q (once)
#pragma unroll
    for (int rep = 0; rep < 4; ++rep) {
        int c = rep * 256 + tid;
        int qr = c >> 3, d0 = (c & 7) * 8;
        GL16(Qbase + (size_t)qr * 512 + d0, &lQ[c * 8]);
    }
    if (tid < 128) { m_s[tid] = -3.0e38f; l_s[tid] = 0.f; }
    __syncthreads();

    bf16x8 af[4][2];
#pragma unroll
    for (int i = 0; i < 4; i++)
#pragma unroll
        for (int s = 0; s < 2; s++)
            af[i][s] = *(const bf16x8*)&lQ[(wm * 64 + i * 16 + rl) * 64 + s * 32 + kq * 8];

    f32x4 o[4][2];
#pragma unroll
    for (int i = 0; i < 4; i++)
#pragma unroll
        for (int jj = 0; jj < 2; jj++) o[i][jj] = (f32x4){0.f, 0.f, 0.f, 0.f};

    for (int t = 0; t < 4; ++t) {
        int kv0 = t * 128;
        __syncthreads();   // prior PV reads of lPK/lVt done
        // stage K tile -> lPK (linear [kv][64])
        const u16* Kbase = Kb0 + (size_t)kv0 * 512;
#pragma unroll
        for (int rep = 0; rep < 4; ++rep) {
            int c = rep * 256 + tid;
            int kv = c >> 3, d0 = (c & 7) * 8;
            GL16(Kbase + (size_t)kv * 512 + d0, &lPK[c * 8]);
        }
        // stage V^T (paired-row b32 writes, bank = p%32 -> 2-way, free)
        const u16* Vbase = Vb0 + (size_t)kv0 * 512;
#pragma unroll
        for (int rep = 0; rep < 2; ++rep) {
            int idx = rep * 256 + tid;
            int p = idx & 63, e0 = (idx >> 6) * 8;
            const u16* vp0 = Vbase + (size_t)(2 * p) * 512 + e0;
            u16x8 v0 = *(const u16x8*)vp0;
            u16x8 v1 = *(const u16x8*)(vp0 + 512);
#pragma unroll
            for (int u = 0; u < 8; ++u)
                lVt[(e0 + u) * 68 + p] = (unsigned)v0[u] | ((unsigned)v1[u] << 16);
        }
        __syncthreads();   // staging complete

        // S = Q K^T * 0.125 + bias
        f32x4 acc[4][4];
#pragma unroll
        for (int j = 0; j < 4; ++j) {
            bf16x8 bk0 = *(const bf16x8*)&lPK[(wn * 64 + j * 16 + rl) * 64 + kq * 8];
            bf16x8 bk1 = *(const bf16x8*)&lPK[(wn * 64 + j * 16 + rl) * 64 + 32 + kq * 8];
#pragma unroll
            for (int i = 0; i < 4; ++i) {
                acc[i][j] = __builtin_amdgcn_mfma_f32_16x16x32_bf16(af[i][0], bk0,
                            (f32x4){0.f, 0.f, 0.f, 0.f}, 0, 0, 0);
                acc[i][j] = __builtin_amdgcn_mfma_f32_16x16x32_bf16(af[i][1], bk1, acc[i][j], 0, 0, 0);
            }
        }
#pragma unroll
        for (int i = 0; i < 4; ++i)
#pragma unroll
            for (int j = 0; j < 4; ++j) {
                int colg = kv0 + wn * 64 + j * 16 + rl;
                const float* bp = biasP + (size_t)(qg0 + wm * 64 + i * 16 + kq * 4) * 512 + colg;
#pragma unroll
                for (int r = 0; r < 4; ++r)
                    acc[i][j][r] = acc[i][j][r] * 0.125f + bp[(size_t)r * 512];
            }

        // per-tile row max -> red
#pragma unroll
        for (int i = 0; i < 4; ++i) {
            float mx[4];
#pragma unroll
            for (int r = 0; r < 4; ++r) {
                mx[r] = fmaxf(fmaxf(acc[i][0][r], acc[i][1][r]), fmaxf(acc[i][2][r], acc[i][3][r]));
#pragma unroll
                for (int off = 8; off > 0; off >>= 1) mx[r] = fmaxf(mx[r], __shfl_xor(mx[r], off));
            }
            if (rl == 0) {
#pragma unroll
                for (int r = 0; r < 4; ++r)
                    red[wn * 128 + wm * 64 + i * 16 + kq * 4 + r] = mx[r];
            }
        }
        __syncthreads();
        if (tid < 128) {
            float pm = fmaxf(red[tid], red[128 + tid]);
            float mo = m_s[tid];
            float mn = fmaxf(mo, pm);
            m_s[tid] = mn; mnew_s[tid] = mn;
            alpha_s[tid] = __expf(mo - mn);
        }
        __syncthreads();

        // P = exp(S - m_new); write lP; row sums; rescale O
#pragma unroll
        for (int i = 0; i < 4; ++i) {
            int rb = wm * 64 + i * 16 + kq * 4;
            float mn[4], al[4], sm[4];
#pragma unroll
            for (int r = 0; r < 4; ++r) { mn[r] = mnew_s[rb + r]; al[r] = alpha_s[rb + r]; sm[r] = 0.f; }
#pragma unroll
            for (int j = 0; j < 4; ++j) {
                int col = wn * 64 + j * 16 + rl;
#pragma unroll
                for (int r = 0; r < 4; ++r) {
                    float p = __expf(acc[i][j][r] - mn[r]);
                    sm[r] += p;
                    lPK[(rb + r) * 136 + col] = f2bf(p);
                }
            }
#pragma unroll
            for (int jj = 0; jj < 2; ++jj)
#pragma unroll
                for (int r = 0; r < 4; ++r) o[i][jj][r] *= al[r];
#pragma unroll
            for (int r = 0; r < 4; ++r) {
#pragma unroll
                for (int off = 8; off > 0; off >>= 1) sm[r] += __shfl_xor(sm[r], off);
            }
            if (rl == 0) {
#pragma unroll
                for (int r = 0; r < 4; ++r) red[wn * 128 + rb + r] = sm[r];
            }
        }
        __syncthreads();
        if (tid < 128) l_s[tid] = l_s[tid] * alpha_s[tid] + red[tid] + red[128 + tid];

        // O += P V  (A-frags from lP stride 136; B-frags from lVt:
        //  kv pairs packed in u32 -> u32 offset X must satisfy 2X = ks*32+kq*8)
#pragma unroll
        for (int ks = 0; ks < 4; ++ks) {
            bf16x8 aP[4], bV[2];
#pragma unroll
            for (int i = 0; i < 4; ++i)
                aP[i] = *(const bf16x8*)&lPK[(wm * 64 + i * 16 + rl) * 136 + ks * 32 + kq * 8];
#pragma unroll
            for (int jj = 0; jj < 2; ++jj)
                bV[jj] = *(const bf16x8*)&lVt[(wn * 32 + jj * 16 + rl) * 68 + ks * 16 + kq * 4];
#pragma unroll
            for (int i = 0; i < 4; ++i)
#pragma unroll
                for (int jj = 0; jj < 2; ++jj)
                    o[i][jj] = __builtin_amdgcn_mfma_f32_16x16x32_bf16(aP[i], bV[jj], o[i][jj], 0, 0, 0);
        }
    }
    __syncthreads();

    // epilogue: O /= l, write bf16
    u16* Ob = O + hb + (size_t)qg0 * 512;
#pragma unroll
    for (int i = 0; i < 4; ++i) {
        int rb = wm * 64 + i * 16 + kq * 4;
        float il[4];
#pragma unroll
        for (int r = 0; r < 4; ++r) il[r] = 1.f / l_s[rb + r];
#pragma unroll
        for (int jj = 0; jj < 2; ++jj) {
            int e = wn * 32 + jj * 16 + rl;
#pragma unroll
            for (int r = 0; r < 4; ++r)
                Ob[(size_t)(rb + r) * 512 + e] = f2bf(o[i][jj][r] * il[r]);
        }
    }
}

// ---------------------------------------------------------------------------
extern "C" void kernel_launch(void* const* d_in, const int* in_sizes, int n_in,
                              void* d_out, int out_size, void* d_ws, size_t ws_size,
                              hipStream_t stream)
{
    const float* x     = (const float*)d_in[0];
    const float* lap   = (const float*)d_in[1];
    const float* emb   = (const float*)d_in[2];
    const float* Wq    = (const float*)d_in[3];
    const float* bq    = (const float*)d_in[4];
    const float* Wk    = (const float*)d_in[5];
    const float* bk    = (const float*)d_in[6];
    const float* Wv    = (const float*)d_in[7];
    const float* bvv   = (const float*)d_in[8];
    const float* g1    = (const float*)d_in[9];
    const float* bb1   = (const float*)d_in[10];
    const float* g2    = (const float*)d_in[11];
    const float* bb2   = (const float*)d_in[12];
    const float* alpha = (const float*)d_in[13];
    const float* beta  = (const float*)d_in[14];
    const float* Wo    = (const float*)d_in[15];
    const float* bo    = (const float*)d_in[16];
    const float* W1    = (const float*)d_in[17];
    const float* b1    = (const float*)d_in[18];
    const float* W2    = (const float*)d_in[19];
    const float* b2    = (const float*)d_in[20];
    float* out = (float*)d_out;

    const size_t SZ = (size_t)4 * 8 * 512 * 512;
    char* w = (char*)d_ws;
    float* bias = (float*)w;  w += (size_t)512 * 512 * 4;
    u16* wqb = (u16*)w; w += (size_t)512 * 512 * 2;
    u16* wkb = (u16*)w; w += (size_t)512 * 512 * 2;
    u16* wvb = (u16*)w; w += (size_t)512 * 512 * 2;
    u16* wob = (u16*)w; w += (size_t)512 * 512 * 2;
    u16* w1b = (u16*)w; w += (size_t)2048 * 512 * 2;
    u16* w2b = (u16*)w; w += (size_t)512 * 2048 * 2;
    u16* xnb = (u16*)w; w += SZ * 2;   // LN1 out; reused as attention output
    u16* qb  = (u16*)w; w += SZ * 2;   // Q; reused as LN2 out
    u16* kb  = (u16*)w; w += SZ * 2;
    u16* vb  = (u16*)w; w += SZ * 2;
    u16* hb  = (u16*)w; w += (size_t)16384 * 2048 * 2;
    float* x1 = out;

    const int M = 16384;
    cvt6_kernel<<<1536, 256, 0, stream>>>(Wq, Wk, Wv, Wo, W1, W2,
                                          wqb, wkb, wvb, wob, w1b, w2b);
    bias_kernel<<<512, 256, 0, stream>>>(emb, lap, alpha, beta, bias);
    ln_kernel<<<M / 4, 256, 0, stream>>>(x, g1, bb1, xnb);
    gemm_qkv<<<dim3(12, 128), 256, 0, stream>>>(xnb, wqb, wkb, wvb, bq, bk, bvv, qb, kb, vb);
    flash_attn<<<dim3(4, 8, 32), 256, 0, stream>>>(qb, kb, vb, bias, xnb);
    gemm_bt<<<dim3(4, 128), 256, 0, stream>>>(xnb, wob, bo, x, nullptr, x1, M, 512, 512, 2);
    ln_kernel<<<M / 4, 256, 0, stream>>>(x1, g2, bb2, qb);
    gemm_bt<<<dim3(16, 128), 256, 0, stream>>>(qb, w1b, b1, nullptr, hb, nullptr, M, 512, 2048, 1);
    gemm_bt<<<dim3(4, 128), 256, 0, stream>>>(hb, w2b, b2, x1, nullptr, out, M, 2048, 512, 2);
}